// Round 2
// baseline (901.820 us; speedup 1.0000x reference)
//
#include <hip/hip_runtime.h>
#include <math.h>

#define N_NODE   100000
#define N_EDGE   500000
#define IN_DIM   128
#define OUT_DIM  128
#define ATTN_DIM 64
#define N_RELTAB 401   // 2*N_REL+1
#define N_QRY    64
#define N_TAU    366

// ---------------------------------------------------------------------------
// Kernel 1: build small lookup tables
// ---------------------------------------------------------------------------
__global__ void build_tables(const int* __restrict__ q_rel,
                             const int* __restrict__ q_tau_p,
                             const float* __restrict__ rela_embed,
                             const float* __restrict__ Wr_w,
                             const float* __restrict__ Wqr_w,
                             const float* __restrict__ Wqr_b,
                             const float* __restrict__ Wtau_w,
                             const float* __restrict__ w_t1,
                             const float* __restrict__ b_t1,
                             const float* __restrict__ w_t2,
                             const float* __restrict__ b_t2,
                             float* __restrict__ rel_attn,
                             float* __restrict__ qr_attn,
                             float* __restrict__ h_tau_tab,
                             float* __restrict__ tau_attn) {
    __shared__ float srow[IN_DIM];
    const int b = blockIdx.x;
    const int t = threadIdx.x;   // 0..127

    if (b < N_TAU) {
        const int q_tau = *q_tau_p;
        const float delta = (float)(b - q_tau);
        float v = w_t1[t] * delta + b_t1[t] + sinf(w_t2[t] * delta + b_t2[t]);
        h_tau_tab[b * IN_DIM + t] = v;
        srow[t] = v;
        __syncthreads();
        if (t < ATTN_DIM) {
            float acc = 0.f;
            #pragma unroll 8
            for (int d = 0; d < IN_DIM; ++d)
                acc += srow[d] * Wtau_w[d * ATTN_DIM + t];
            tau_attn[b * ATTN_DIM + t] = acc;
        }
    } else if (b < N_TAU + N_RELTAB) {
        const int r = b - N_TAU;
        srow[t] = rela_embed[r * IN_DIM + t];
        __syncthreads();
        if (t < ATTN_DIM) {
            float acc = 0.f;
            #pragma unroll 8
            for (int d = 0; d < IN_DIM; ++d)
                acc += srow[d] * Wr_w[d * ATTN_DIM + t];
            rel_attn[r * ATTN_DIM + t] = acc;
        }
    } else {
        const int i = b - N_TAU - N_RELTAB;   // 0..63
        const int r = q_rel[i];
        srow[t] = rela_embed[r * IN_DIM + t];
        __syncthreads();
        if (t < ATTN_DIM) {
            float acc = Wqr_b[t];
            #pragma unroll 8
            for (int d = 0; d < IN_DIM; ++d)
                acc += srow[d] * Wqr_w[d * ATTN_DIM + t];
            qr_attn[i * ATTN_DIM + t] = acc;
        }
    }
}

// ---------------------------------------------------------------------------
// Kernel 2: A_node = hidden @ Ws_w   (100k x 128) @ (128 x 64)
// ---------------------------------------------------------------------------
__global__ __launch_bounds__(256) void node_attn(const float* __restrict__ hidden,
                                                 const float* __restrict__ Ws_w,
                                                 float* __restrict__ A_node) {
    const int wave = threadIdx.x >> 6;
    const int lane = threadIdx.x & 63;
    const int node = blockIdx.x * 4 + wave;
    const float* h = hidden + (size_t)node * IN_DIM;
    const float2 hv = *(const float2*)(h + 2 * lane);   // lane l holds h[2l], h[2l+1]
    float acc = 0.f;
    #pragma unroll
    for (int d = 0; d < IN_DIM; ++d) {
        float x = __shfl((d & 1) ? hv.y : hv.x, d >> 1, 64);
        acc += x * Ws_w[d * ATTN_DIM + lane];
    }
    A_node[(size_t)node * ATTN_DIM + lane] = acc;
}

// ---------------------------------------------------------------------------
// Kernel 3: histogram of obj
// ---------------------------------------------------------------------------
__global__ __launch_bounds__(256) void count_edges(const int* __restrict__ edges,
                                                   int* __restrict__ count) {
    const int e = blockIdx.x * 256 + threadIdx.x;
    if (e < N_EDGE) {
        const int obj = edges[(size_t)e * 7 + 6];
        atomicAdd(&count[obj], 1);
    }
}

// ---------------------------------------------------------------------------
// Kernel 4: exclusive scan of counts -> off[100001], cursor[100000]
// Single block, 1024 threads, chunked serial + Hillis-Steele over partials.
// ---------------------------------------------------------------------------
__global__ __launch_bounds__(1024) void scan_offsets(const int* __restrict__ count,
                                                     int* __restrict__ off,
                                                     int* __restrict__ cursor) {
    __shared__ int part[1024];
    const int t = threadIdx.x;
    const int CH = 98;                       // 98*1024 >= 100000
    const int base = t * CH;
    int s = 0;
    for (int i = 0; i < CH; ++i) {
        const int idx = base + i;
        if (idx < N_NODE) s += count[idx];
    }
    part[t] = s;
    __syncthreads();
    for (int d = 1; d < 1024; d <<= 1) {
        int v = (t >= d) ? part[t - d] : 0;
        __syncthreads();
        part[t] += v;
        __syncthreads();
    }
    int run = (t == 0) ? 0 : part[t - 1];
    for (int i = 0; i < CH; ++i) {
        const int idx = base + i;
        if (idx < N_NODE) {
            off[idx] = run;
            cursor[idx] = run;
            run += count[idx];
        }
    }
    if (t == 1023) off[N_NODE] = run;        // = 500000
}

// ---------------------------------------------------------------------------
// Kernel 5: per-edge attention alpha + CSR fill.
// One wave per edge; lane = attn dim. Lane 0 claims a slot and stores the
// packed record {sub, rel, tidx, alpha_bits}.
// ---------------------------------------------------------------------------
__global__ __launch_bounds__(256) void alpha_fill(const int* __restrict__ edges,
                                                  const int* __restrict__ q_tau_p,
                                                  const float* __restrict__ A_node,
                                                  const float* __restrict__ rel_attn,
                                                  const float* __restrict__ qr_attn,
                                                  const float* __restrict__ tau_attn,
                                                  const float* __restrict__ w_alpha_w,
                                                  const float* __restrict__ w_alpha_b,
                                                  int* __restrict__ cursor,
                                                  int4* __restrict__ recs) {
    const int wave = threadIdx.x >> 6;
    const int lane = threadIdx.x & 63;
    const int e = blockIdx.x * 4 + wave;
    const int* ed = edges + (size_t)e * 7;
    const int r_idx = ed[0];
    const int rel   = ed[2];
    const int tau   = ed[4];
    const int sub   = ed[5];
    const int obj   = ed[6];
    const int q_tau = *q_tau_p;
    const int tidx  = (tau >= 0) ? tau : q_tau;

    float a = A_node[(size_t)sub * ATTN_DIM + lane]
            + rel_attn[rel * ATTN_DIM + lane]
            + qr_attn[r_idx * ATTN_DIM + lane]
            + tau_attn[tidx * ATTN_DIM + lane];
    a = fmaxf(a, 0.f) * w_alpha_w[lane];
    #pragma unroll
    for (int off = 32; off > 0; off >>= 1)
        a += __shfl_xor(a, off, 64);
    const float alpha = 1.f / (1.f + __expf(-(a + w_alpha_b[0])));

    if (lane == 0) {
        const int pos = atomicAdd(&cursor[obj], 1);
        recs[pos] = make_int4(sub, rel, tidx, __float_as_int(alpha));
    }
}

// ---------------------------------------------------------------------------
// Kernel 6: per-node gather-aggregate. One wave per node; lane holds dims
// {2*lane, 2*lane+1}. Writes agg and agg_s rows exactly once (zeros if deg 0).
// ---------------------------------------------------------------------------
__global__ __launch_bounds__(256) void aggregate(const int* __restrict__ off,
                                                 const int4* __restrict__ recs,
                                                 const float* __restrict__ hidden,
                                                 const float* __restrict__ rela_embed,
                                                 const float* __restrict__ h_tau_tab,
                                                 float* __restrict__ agg,
                                                 float* __restrict__ agg_s) {
    const int wave = threadIdx.x >> 6;
    const int lane = threadIdx.x & 63;
    const int n = blockIdx.x * 4 + wave;
    const int j0 = off[n];
    const int j1 = off[n + 1];

    float t0 = 0.f, t1 = 0.f;   // sum m
    float a0 = 0.f, a1 = 0.f;   // sum alpha*m
    for (int j = j0; j < j1; ++j) {
        const int4 rec = recs[j];
        const float alpha = __int_as_float(rec.w);
        const float2 h = *(const float2*)&hidden[(size_t)rec.x * IN_DIM + 2 * lane];
        const float2 r = *(const float2*)&rela_embed[(size_t)rec.y * IN_DIM + 2 * lane];
        const float2 u = *(const float2*)&h_tau_tab[(size_t)rec.z * IN_DIM + 2 * lane];
        const float m0 = h.x + r.x + u.x;
        const float m1 = h.y + r.y + u.y;
        t0 += m0; t1 += m1;
        a0 = fmaf(alpha, m0, a0);
        a1 = fmaf(alpha, m1, a1);
    }
    float2* po  = (float2*)&agg[(size_t)n * OUT_DIM + 2 * lane];
    float2* ps  = (float2*)&agg_s[(size_t)n * OUT_DIM + 2 * lane];
    *po = make_float2(a0, a1);
    *ps = make_float2(t0 - a0, t1 - a1);
}

// ---------------------------------------------------------------------------
// Kernel 7: in-place row transform  out_row <- out_row @ W  (per half).
// ---------------------------------------------------------------------------
__global__ __launch_bounds__(256) void final_gemm(float* __restrict__ out,
                                                  const float* __restrict__ W_h_w,
                                                  const float* __restrict__ W_h_s_w) {
    const int half = blockIdx.x & 1;
    const int tile = blockIdx.x >> 1;          // 0 .. 3124
    const int row0 = tile * 32;
    float* buf = out + (size_t)half * N_NODE * OUT_DIM;
    const float* __restrict__ W = half ? W_h_s_w : W_h_w;

    __shared__ float lds[32 * 132];
    for (int i = threadIdx.x; i < 32 * 32; i += 256) {
        const int r = i >> 5, c4 = (i & 31) << 2;
        *(float4*)&lds[r * 132 + c4] = *(const float4*)&buf[(size_t)(row0 + r) * 128 + c4];
    }
    __syncthreads();

    const int cl = threadIdx.x & 63;
    const int rg = threadIdx.x >> 6;           // 0..3
    float acc0[8] = {0,0,0,0,0,0,0,0};
    float acc1[8] = {0,0,0,0,0,0,0,0};

    for (int k = 0; k < 128; k += 4) {
        float wA[4], wB[4];
        #pragma unroll
        for (int j = 0; j < 4; ++j) {
            wA[j] = W[(k + j) * 128 + cl];
            wB[j] = W[(k + j) * 128 + cl + 64];
        }
        #pragma unroll
        for (int r = 0; r < 8; ++r) {
            const float4 v = *(const float4*)&lds[(rg * 8 + r) * 132 + k];
            acc0[r] += v.x * wA[0] + v.y * wA[1] + v.z * wA[2] + v.w * wA[3];
            acc1[r] += v.x * wB[0] + v.y * wB[1] + v.z * wB[2] + v.w * wB[3];
        }
    }

    #pragma unroll
    for (int r = 0; r < 8; ++r) {
        buf[(size_t)(row0 + rg * 8 + r) * 128 + cl]      = acc0[r];
        buf[(size_t)(row0 + rg * 8 + r) * 128 + cl + 64] = acc1[r];
    }
}

// ---------------------------------------------------------------------------
extern "C" void kernel_launch(void* const* d_in, const int* in_sizes, int n_in,
                              void* d_out, int out_size, void* d_ws, size_t ws_size,
                              hipStream_t stream) {
    const int*   q_rel      = (const int*)d_in[1];
    const int*   q_tau_p    = (const int*)d_in[2];
    const float* hidden     = (const float*)d_in[3];
    const int*   edges      = (const int*)d_in[4];
    const float* rela_embed = (const float*)d_in[7];
    const float* Ws_w       = (const float*)d_in[8];
    const float* Wr_w       = (const float*)d_in[9];
    const float* Wqr_w      = (const float*)d_in[10];
    const float* Wqr_b      = (const float*)d_in[11];
    const float* Wtau_w     = (const float*)d_in[12];
    const float* w_alpha_w  = (const float*)d_in[13];
    const float* w_alpha_b  = (const float*)d_in[14];
    const float* W_h_w      = (const float*)d_in[15];
    const float* W_h_s_w    = (const float*)d_in[16];
    const float* w_t1       = (const float*)d_in[17];
    const float* b_t1       = (const float*)d_in[18];
    const float* w_t2       = (const float*)d_in[19];
    const float* b_t2       = (const float*)d_in[20];

    // workspace layout
    float* ws       = (float*)d_ws;
    float* A_node   = ws;                                   // 100000*64
    float* rel_attn = A_node + (size_t)N_NODE * ATTN_DIM;   // 401*64
    float* qr_attn  = rel_attn + N_RELTAB * ATTN_DIM;       // 64*64
    float* h_tau    = qr_attn + N_QRY * ATTN_DIM;           // 366*128
    float* tau_attn = h_tau + N_TAU * IN_DIM;               // 366*64
    int*   count    = (int*)(tau_attn + N_TAU * ATTN_DIM);  // 100000
    int*   off      = count + N_NODE;                       // 100001
    int*   cursor   = off + N_NODE + 1;                     // 100000
    // align recs to 16B
    size_t rec_off  = ((size_t)(cursor + N_NODE) - (size_t)d_ws + 15) & ~(size_t)15;
    int4*  recs     = (int4*)((char*)d_ws + rec_off);       // 500000 * 16B

    float* agg   = (float*)d_out;
    float* agg_s = (float*)d_out + (size_t)N_NODE * OUT_DIM;

    hipMemsetAsync(count, 0, (size_t)N_NODE * sizeof(int), stream);

    build_tables<<<dim3(N_TAU + N_RELTAB + N_QRY), dim3(128), 0, stream>>>(
        q_rel, q_tau_p, rela_embed, Wr_w, Wqr_w, Wqr_b, Wtau_w,
        w_t1, b_t1, w_t2, b_t2, rel_attn, qr_attn, h_tau, tau_attn);

    node_attn<<<dim3(N_NODE / 4), dim3(256), 0, stream>>>(hidden, Ws_w, A_node);

    count_edges<<<dim3((N_EDGE + 255) / 256), dim3(256), 0, stream>>>(edges, count);

    scan_offsets<<<dim3(1), dim3(1024), 0, stream>>>(count, off, cursor);

    alpha_fill<<<dim3(N_EDGE / 4), dim3(256), 0, stream>>>(
        edges, q_tau_p, A_node, rel_attn, qr_attn, tau_attn,
        w_alpha_w, w_alpha_b, cursor, recs);

    aggregate<<<dim3(N_NODE / 4), dim3(256), 0, stream>>>(
        off, recs, hidden, rela_embed, h_tau, agg, agg_s);

    final_gemm<<<dim3(2 * (N_NODE / 32)), dim3(256), 0, stream>>>(
        (float*)d_out, W_h_w, W_h_s_w);
}

// Round 3
// 653.717 us; speedup vs baseline: 1.3795x; 1.3795x over previous
//
#include <hip/hip_runtime.h>
#include <math.h>

#define N_NODE   100000
#define N_EDGE   500000
#define IN_DIM   128
#define OUT_DIM  128
#define ATTN_DIM 64
#define N_RELTAB 401   // 2*N_REL+1
#define N_QRY    64
#define N_TAU    366

#define SCAN_BLK     256
#define N_SCAN_BLKS  ((N_NODE + SCAN_BLK - 1) / SCAN_BLK)   // 391

// ---------------------------------------------------------------------------
// Kernel 1: build small lookup tables
// ---------------------------------------------------------------------------
__global__ void build_tables(const int* __restrict__ q_rel,
                             const int* __restrict__ q_tau_p,
                             const float* __restrict__ rela_embed,
                             const float* __restrict__ Wr_w,
                             const float* __restrict__ Wqr_w,
                             const float* __restrict__ Wqr_b,
                             const float* __restrict__ Wtau_w,
                             const float* __restrict__ w_t1,
                             const float* __restrict__ b_t1,
                             const float* __restrict__ w_t2,
                             const float* __restrict__ b_t2,
                             float* __restrict__ rel_attn,
                             float* __restrict__ qr_attn,
                             float* __restrict__ h_tau_tab,
                             float* __restrict__ tau_attn) {
    __shared__ float srow[IN_DIM];
    const int b = blockIdx.x;
    const int t = threadIdx.x;   // 0..127

    if (b < N_TAU) {
        const int q_tau = *q_tau_p;
        const float delta = (float)(b - q_tau);
        float v = w_t1[t] * delta + b_t1[t] + sinf(w_t2[t] * delta + b_t2[t]);
        h_tau_tab[b * IN_DIM + t] = v;
        srow[t] = v;
        __syncthreads();
        if (t < ATTN_DIM) {
            float acc = 0.f;
            #pragma unroll 8
            for (int d = 0; d < IN_DIM; ++d)
                acc += srow[d] * Wtau_w[d * ATTN_DIM + t];
            tau_attn[b * ATTN_DIM + t] = acc;
        }
    } else if (b < N_TAU + N_RELTAB) {
        const int r = b - N_TAU;
        srow[t] = rela_embed[r * IN_DIM + t];
        __syncthreads();
        if (t < ATTN_DIM) {
            float acc = 0.f;
            #pragma unroll 8
            for (int d = 0; d < IN_DIM; ++d)
                acc += srow[d] * Wr_w[d * ATTN_DIM + t];
            rel_attn[r * ATTN_DIM + t] = acc;
        }
    } else {
        const int i = b - N_TAU - N_RELTAB;   // 0..63
        const int r = q_rel[i];
        srow[t] = rela_embed[r * IN_DIM + t];
        __syncthreads();
        if (t < ATTN_DIM) {
            float acc = Wqr_b[t];
            #pragma unroll 8
            for (int d = 0; d < IN_DIM; ++d)
                acc += srow[d] * Wqr_w[d * ATTN_DIM + t];
            qr_attn[i * ATTN_DIM + t] = acc;
        }
    }
}

// ---------------------------------------------------------------------------
// Kernel 2: A_node = hidden @ Ws_w   (100k x 128) @ (128 x 64)
// ---------------------------------------------------------------------------
__global__ __launch_bounds__(256) void node_attn(const float* __restrict__ hidden,
                                                 const float* __restrict__ Ws_w,
                                                 float* __restrict__ A_node) {
    const int wave = threadIdx.x >> 6;
    const int lane = threadIdx.x & 63;
    const int node = blockIdx.x * 4 + wave;
    const float* h = hidden + (size_t)node * IN_DIM;
    const float2 hv = *(const float2*)(h + 2 * lane);   // lane l holds h[2l], h[2l+1]
    float acc = 0.f;
    #pragma unroll
    for (int d = 0; d < IN_DIM; ++d) {
        float x = __shfl((d & 1) ? hv.y : hv.x, d >> 1, 64);
        acc += x * Ws_w[d * ATTN_DIM + lane];
    }
    A_node[(size_t)node * ATTN_DIM + lane] = acc;
}

// ---------------------------------------------------------------------------
// Kernel 3: histogram of obj
// ---------------------------------------------------------------------------
__global__ __launch_bounds__(256) void count_edges(const int* __restrict__ edges,
                                                   int* __restrict__ count) {
    const int e = blockIdx.x * 256 + threadIdx.x;
    if (e < N_EDGE) {
        const int obj = edges[(size_t)e * 7 + 6];
        atomicAdd(&count[obj], 1);
    }
}

// ---------------------------------------------------------------------------
// Kernel 4a: per-block partial sums of count
// ---------------------------------------------------------------------------
__global__ __launch_bounds__(SCAN_BLK) void scan_partial(const int* __restrict__ count,
                                                         int* __restrict__ partial) {
    __shared__ int lds[SCAN_BLK];
    const int i = blockIdx.x * SCAN_BLK + threadIdx.x;
    lds[threadIdx.x] = (i < N_NODE) ? count[i] : 0;
    __syncthreads();
    for (int s = SCAN_BLK / 2; s > 0; s >>= 1) {
        if (threadIdx.x < s) lds[threadIdx.x] += lds[threadIdx.x + s];
        __syncthreads();
    }
    if (threadIdx.x == 0) partial[blockIdx.x] = lds[0];
}

// ---------------------------------------------------------------------------
// Kernel 4b: exclusive scan of the 391 block partials
// ---------------------------------------------------------------------------
__global__ __launch_bounds__(512) void scan_partials(const int* __restrict__ partial,
                                                     int* __restrict__ blk_off) {
    __shared__ int lds[512];
    const int t = threadIdx.x;
    lds[t] = (t < N_SCAN_BLKS) ? partial[t] : 0;
    __syncthreads();
    for (int d = 1; d < 512; d <<= 1) {
        int v = (t >= d) ? lds[t - d] : 0;
        __syncthreads();
        lds[t] += v;
        __syncthreads();
    }
    if (t < N_SCAN_BLKS) blk_off[t] = (t == 0) ? 0 : lds[t - 1];
}

// ---------------------------------------------------------------------------
// Kernel 4c: per-block scan + apply block offset -> off, cursor
// ---------------------------------------------------------------------------
__global__ __launch_bounds__(SCAN_BLK) void scan_apply(const int* __restrict__ count,
                                                       const int* __restrict__ blk_off,
                                                       int* __restrict__ off,
                                                       int* __restrict__ cursor) {
    __shared__ int lds[SCAN_BLK];
    const int t = threadIdx.x;
    const int i = blockIdx.x * SCAN_BLK + t;
    const int v = (i < N_NODE) ? count[i] : 0;
    lds[t] = v;
    __syncthreads();
    for (int d = 1; d < SCAN_BLK; d <<= 1) {
        int x = (t >= d) ? lds[t - d] : 0;
        __syncthreads();
        lds[t] += x;
        __syncthreads();
    }
    const int excl = blk_off[blockIdx.x] + lds[t] - v;
    if (i < N_NODE) { off[i] = excl; cursor[i] = excl; }
    if (i == N_NODE - 1) off[N_NODE] = excl + v;   // = N_EDGE
}

// ---------------------------------------------------------------------------
// Kernel 5: per-edge attention alpha + CSR fill.
// ---------------------------------------------------------------------------
__global__ __launch_bounds__(256) void alpha_fill(const int* __restrict__ edges,
                                                  const int* __restrict__ q_tau_p,
                                                  const float* __restrict__ A_node,
                                                  const float* __restrict__ rel_attn,
                                                  const float* __restrict__ qr_attn,
                                                  const float* __restrict__ tau_attn,
                                                  const float* __restrict__ w_alpha_w,
                                                  const float* __restrict__ w_alpha_b,
                                                  int* __restrict__ cursor,
                                                  int4* __restrict__ recs) {
    const int wave = threadIdx.x >> 6;
    const int lane = threadIdx.x & 63;
    const int e = blockIdx.x * 4 + wave;
    const int* ed = edges + (size_t)e * 7;
    const int r_idx = ed[0];
    const int rel   = ed[2];
    const int tau   = ed[4];
    const int sub   = ed[5];
    const int obj   = ed[6];
    const int q_tau = *q_tau_p;
    const int tidx  = (tau >= 0) ? tau : q_tau;

    float a = A_node[(size_t)sub * ATTN_DIM + lane]
            + rel_attn[rel * ATTN_DIM + lane]
            + qr_attn[r_idx * ATTN_DIM + lane]
            + tau_attn[tidx * ATTN_DIM + lane];
    a = fmaxf(a, 0.f) * w_alpha_w[lane];
    #pragma unroll
    for (int off = 32; off > 0; off >>= 1)
        a += __shfl_xor(a, off, 64);
    const float alpha = 1.f / (1.f + __expf(-(a + w_alpha_b[0])));

    if (lane == 0) {
        const int pos = atomicAdd(&cursor[obj], 1);
        recs[pos] = make_int4(sub, rel, tidx, __float_as_int(alpha));
    }
}

// ---------------------------------------------------------------------------
// Kernel 6: per-node gather-aggregate. One wave per node.
// ---------------------------------------------------------------------------
__global__ __launch_bounds__(256) void aggregate(const int* __restrict__ off,
                                                 const int4* __restrict__ recs,
                                                 const float* __restrict__ hidden,
                                                 const float* __restrict__ rela_embed,
                                                 const float* __restrict__ h_tau_tab,
                                                 float* __restrict__ agg,
                                                 float* __restrict__ agg_s) {
    const int wave = threadIdx.x >> 6;
    const int lane = threadIdx.x & 63;
    const int n = blockIdx.x * 4 + wave;
    const int j0 = off[n];
    const int j1 = off[n + 1];

    float t0 = 0.f, t1 = 0.f;   // sum m
    float a0 = 0.f, a1 = 0.f;   // sum alpha*m
    for (int j = j0; j < j1; ++j) {
        const int4 rec = recs[j];
        const float alpha = __int_as_float(rec.w);
        const float2 h = *(const float2*)&hidden[(size_t)rec.x * IN_DIM + 2 * lane];
        const float2 r = *(const float2*)&rela_embed[(size_t)rec.y * IN_DIM + 2 * lane];
        const float2 u = *(const float2*)&h_tau_tab[(size_t)rec.z * IN_DIM + 2 * lane];
        const float m0 = h.x + r.x + u.x;
        const float m1 = h.y + r.y + u.y;
        t0 += m0; t1 += m1;
        a0 = fmaf(alpha, m0, a0);
        a1 = fmaf(alpha, m1, a1);
    }
    float2* po  = (float2*)&agg[(size_t)n * OUT_DIM + 2 * lane];
    float2* ps  = (float2*)&agg_s[(size_t)n * OUT_DIM + 2 * lane];
    *po = make_float2(a0, a1);
    *ps = make_float2(t0 - a0, t1 - a1);
}

// ---------------------------------------------------------------------------
// Kernel 7: in-place row transform  out_row <- out_row @ W  (per half).
// ---------------------------------------------------------------------------
__global__ __launch_bounds__(256) void final_gemm(float* __restrict__ out,
                                                  const float* __restrict__ W_h_w,
                                                  const float* __restrict__ W_h_s_w) {
    const int half = blockIdx.x & 1;
    const int tile = blockIdx.x >> 1;          // 0 .. 3124
    const int row0 = tile * 32;
    float* buf = out + (size_t)half * N_NODE * OUT_DIM;
    const float* __restrict__ W = half ? W_h_s_w : W_h_w;

    __shared__ float lds[32 * 132];
    for (int i = threadIdx.x; i < 32 * 32; i += 256) {
        const int r = i >> 5, c4 = (i & 31) << 2;
        *(float4*)&lds[r * 132 + c4] = *(const float4*)&buf[(size_t)(row0 + r) * 128 + c4];
    }
    __syncthreads();

    const int cl = threadIdx.x & 63;
    const int rg = threadIdx.x >> 6;           // 0..3
    float acc0[8] = {0,0,0,0,0,0,0,0};
    float acc1[8] = {0,0,0,0,0,0,0,0};

    for (int k = 0; k < 128; k += 4) {
        float wA[4], wB[4];
        #pragma unroll
        for (int j = 0; j < 4; ++j) {
            wA[j] = W[(k + j) * 128 + cl];
            wB[j] = W[(k + j) * 128 + cl + 64];
        }
        #pragma unroll
        for (int r = 0; r < 8; ++r) {
            const float4 v = *(const float4*)&lds[(rg * 8 + r) * 132 + k];
            acc0[r] += v.x * wA[0] + v.y * wA[1] + v.z * wA[2] + v.w * wA[3];
            acc1[r] += v.x * wB[0] + v.y * wB[1] + v.z * wB[2] + v.w * wB[3];
        }
    }

    #pragma unroll
    for (int r = 0; r < 8; ++r) {
        buf[(size_t)(row0 + rg * 8 + r) * 128 + cl]      = acc0[r];
        buf[(size_t)(row0 + rg * 8 + r) * 128 + cl + 64] = acc1[r];
    }
}

// ---------------------------------------------------------------------------
extern "C" void kernel_launch(void* const* d_in, const int* in_sizes, int n_in,
                              void* d_out, int out_size, void* d_ws, size_t ws_size,
                              hipStream_t stream) {
    const int*   q_rel      = (const int*)d_in[1];
    const int*   q_tau_p    = (const int*)d_in[2];
    const float* hidden     = (const float*)d_in[3];
    const int*   edges      = (const int*)d_in[4];
    const float* rela_embed = (const float*)d_in[7];
    const float* Ws_w       = (const float*)d_in[8];
    const float* Wr_w       = (const float*)d_in[9];
    const float* Wqr_w      = (const float*)d_in[10];
    const float* Wqr_b      = (const float*)d_in[11];
    const float* Wtau_w     = (const float*)d_in[12];
    const float* w_alpha_w  = (const float*)d_in[13];
    const float* w_alpha_b  = (const float*)d_in[14];
    const float* W_h_w      = (const float*)d_in[15];
    const float* W_h_s_w    = (const float*)d_in[16];
    const float* w_t1       = (const float*)d_in[17];
    const float* b_t1       = (const float*)d_in[18];
    const float* w_t2       = (const float*)d_in[19];
    const float* b_t2       = (const float*)d_in[20];

    // workspace layout
    float* ws       = (float*)d_ws;
    float* A_node   = ws;                                   // 100000*64
    float* rel_attn = A_node + (size_t)N_NODE * ATTN_DIM;   // 401*64
    float* qr_attn  = rel_attn + N_RELTAB * ATTN_DIM;       // 64*64
    float* h_tau    = qr_attn + N_QRY * ATTN_DIM;           // 366*128
    float* tau_attn = h_tau + N_TAU * IN_DIM;               // 366*64
    int*   count    = (int*)(tau_attn + N_TAU * ATTN_DIM);  // 100000
    int*   off      = count + N_NODE;                       // 100001
    int*   cursor   = off + N_NODE + 1;                     // 100000
    int*   partial  = cursor + N_NODE;                      // 391
    int*   blk_off  = partial + N_SCAN_BLKS;                // 391
    size_t rec_off  = ((size_t)(blk_off + N_SCAN_BLKS) - (size_t)d_ws + 15) & ~(size_t)15;
    int4*  recs     = (int4*)((char*)d_ws + rec_off);       // 500000 * 16B

    float* agg   = (float*)d_out;
    float* agg_s = (float*)d_out + (size_t)N_NODE * OUT_DIM;

    hipMemsetAsync(count, 0, (size_t)N_NODE * sizeof(int), stream);

    build_tables<<<dim3(N_TAU + N_RELTAB + N_QRY), dim3(128), 0, stream>>>(
        q_rel, q_tau_p, rela_embed, Wr_w, Wqr_w, Wqr_b, Wtau_w,
        w_t1, b_t1, w_t2, b_t2, rel_attn, qr_attn, h_tau, tau_attn);

    node_attn<<<dim3(N_NODE / 4), dim3(256), 0, stream>>>(hidden, Ws_w, A_node);

    count_edges<<<dim3((N_EDGE + 255) / 256), dim3(256), 0, stream>>>(edges, count);

    scan_partial<<<dim3(N_SCAN_BLKS), dim3(SCAN_BLK), 0, stream>>>(count, partial);
    scan_partials<<<dim3(1), dim3(512), 0, stream>>>(partial, blk_off);
    scan_apply<<<dim3(N_SCAN_BLKS), dim3(SCAN_BLK), 0, stream>>>(count, blk_off, off, cursor);

    alpha_fill<<<dim3(N_EDGE / 4), dim3(256), 0, stream>>>(
        edges, q_tau_p, A_node, rel_attn, qr_attn, tau_attn,
        w_alpha_w, w_alpha_b, cursor, recs);

    aggregate<<<dim3(N_NODE / 4), dim3(256), 0, stream>>>(
        off, recs, hidden, rela_embed, h_tau, agg, agg_s);

    final_gemm<<<dim3(2 * (N_NODE / 32)), dim3(256), 0, stream>>>(
        (float*)d_out, W_h_w, W_h_s_w);
}

// Round 4
// 507.818 us; speedup vs baseline: 1.7759x; 1.2873x over previous
//
#include <hip/hip_runtime.h>
#include <math.h>

#define N_NODE   100000
#define N_EDGE   500000
#define IN_DIM   128
#define OUT_DIM  128
#define ATTN_DIM 64
#define N_RELTAB 401   // 2*N_REL+1
#define N_QRY    64
#define N_TAU    366

#define SCAN_BLK     256
#define N_SCAN_BLKS  ((N_NODE + SCAN_BLK - 1) / SCAN_BLK)   // 391

typedef unsigned int  uint;
typedef unsigned short ushort;
typedef __attribute__((ext_vector_type(8))) short bf16x8;
typedef __attribute__((ext_vector_type(4))) float f32x4;

// ---- bf16 helpers (RNE) ----------------------------------------------------
__device__ __forceinline__ float bfl(uint u)  { return __uint_as_float(u << 16); }
__device__ __forceinline__ float bfh(uint u)  { return __uint_as_float(u & 0xFFFF0000u); }
__device__ __forceinline__ uint  f2bfbits(float f) {
    uint u = __float_as_uint(f);
    return (u + 0x7FFFu + ((u >> 16) & 1u)) >> 16;
}
__device__ __forceinline__ uint  pack2(float lo, float hi) {
    return f2bfbits(lo) | (f2bfbits(hi) << 16);
}

// ---------------------------------------------------------------------------
// Kernel 1: build small lookup tables (all bf16):
//   tau blocks:  tau_msg_bf row (128 dims) + tau_attn_bf row (64 dims)
//   rel blocks:  rel_msg_bf row + rel_attn_bf row
//   qr  blocks:  qr_attn_bf row
//   2 W blocks:  wT_bf = W^T (n-major, k-contiguous) for the MFMA GEMM
// ---------------------------------------------------------------------------
__global__ void build_tables(const int* __restrict__ q_rel,
                             const int* __restrict__ q_tau_p,
                             const float* __restrict__ rela_embed,
                             const float* __restrict__ Wr_w,
                             const float* __restrict__ Wqr_w,
                             const float* __restrict__ Wqr_b,
                             const float* __restrict__ Wtau_w,
                             const float* __restrict__ w_t1,
                             const float* __restrict__ b_t1,
                             const float* __restrict__ w_t2,
                             const float* __restrict__ b_t2,
                             const float* __restrict__ W_h_w,
                             const float* __restrict__ W_h_s_w,
                             uint* __restrict__ rel_attn_bf,   // [401][32]
                             uint* __restrict__ qr_attn_bf,    // [64][32]
                             uint* __restrict__ tau_attn_bf,   // [366][32]
                             uint* __restrict__ rel_msg_bf,    // [401][64]
                             uint* __restrict__ tau_msg_bf,    // [366][64]
                             ushort* __restrict__ wT_bf) {     // [2][128][128]
    __shared__ float srow[IN_DIM];
    __shared__ float sattn[ATTN_DIM];
    const int b = blockIdx.x;
    const int t = threadIdx.x;   // 0..127

    if (b < N_TAU) {
        const int q_tau = *q_tau_p;
        const float delta = (float)(b - q_tau);
        float v = w_t1[t] * delta + b_t1[t] + sinf(w_t2[t] * delta + b_t2[t]);
        srow[t] = v;
        __syncthreads();
        if (t < 64) tau_msg_bf[b * 64 + t] = pack2(srow[2 * t], srow[2 * t + 1]);
        if (t < ATTN_DIM) {
            float acc = 0.f;
            #pragma unroll 8
            for (int d = 0; d < IN_DIM; ++d)
                acc += srow[d] * Wtau_w[d * ATTN_DIM + t];
            sattn[t] = acc;
        }
        __syncthreads();
        if (t < 32) tau_attn_bf[b * 32 + t] = pack2(sattn[2 * t], sattn[2 * t + 1]);
    } else if (b < N_TAU + N_RELTAB) {
        const int r = b - N_TAU;
        srow[t] = rela_embed[r * IN_DIM + t];
        __syncthreads();
        if (t < 64) rel_msg_bf[r * 64 + t] = pack2(srow[2 * t], srow[2 * t + 1]);
        if (t < ATTN_DIM) {
            float acc = 0.f;
            #pragma unroll 8
            for (int d = 0; d < IN_DIM; ++d)
                acc += srow[d] * Wr_w[d * ATTN_DIM + t];
            sattn[t] = acc;
        }
        __syncthreads();
        if (t < 32) rel_attn_bf[r * 32 + t] = pack2(sattn[2 * t], sattn[2 * t + 1]);
    } else if (b < N_TAU + N_RELTAB + N_QRY) {
        const int i = b - N_TAU - N_RELTAB;   // 0..63
        const int r = q_rel[i];
        srow[t] = rela_embed[r * IN_DIM + t];
        __syncthreads();
        if (t < ATTN_DIM) {
            float acc = Wqr_b[t];
            #pragma unroll 8
            for (int d = 0; d < IN_DIM; ++d)
                acc += srow[d] * Wqr_w[d * ATTN_DIM + t];
            sattn[t] = acc;
        }
        __syncthreads();
        if (t < 32) qr_attn_bf[i * 32 + t] = pack2(sattn[2 * t], sattn[2 * t + 1]);
    } else {
        const int w = b - (N_TAU + N_RELTAB + N_QRY);   // 0,1
        const float* Wsrc = w ? W_h_s_w : W_h_w;
        ushort* dst = wT_bf + (size_t)w * 128 * 128;
        // thread t = output col n of W (row of W^T); k-contiguous writes
        for (int k = 0; k < 128; ++k)
            dst[t * 128 + k] = (ushort)f2bfbits(Wsrc[k * 128 + t]);
    }
}

// ---------------------------------------------------------------------------
// Kernel 2: node pass — cast hidden row to bf16 (hid_bf) and compute
// A_node_bf = bf16(hidden @ Ws_w). One wave per node; lane holds dims 2l,2l+1.
// ---------------------------------------------------------------------------
__global__ __launch_bounds__(256) void node_attn(const float* __restrict__ hidden,
                                                 const float* __restrict__ Ws_w,
                                                 uint* __restrict__ hid_bf,     // [N][64]
                                                 uint* __restrict__ A_node_bf) { // [N][32]
    const int wave = threadIdx.x >> 6;
    const int lane = threadIdx.x & 63;
    const int node = blockIdx.x * 4 + wave;
    const float2 hv = *(const float2*)(hidden + (size_t)node * IN_DIM + 2 * lane);
    hid_bf[(size_t)node * 64 + lane] = pack2(hv.x, hv.y);

    float acc = 0.f;
    #pragma unroll
    for (int d = 0; d < IN_DIM; ++d) {
        float x = __shfl((d & 1) ? hv.y : hv.x, d >> 1, 64);
        acc += x * Ws_w[d * ATTN_DIM + lane];
    }
    const int l2 = lane & 31;
    const float e0 = __shfl(acc, 2 * l2, 64);
    const float e1 = __shfl(acc, 2 * l2 + 1, 64);
    if (lane < 32) A_node_bf[(size_t)node * 32 + lane] = pack2(e0, e1);
}

// ---------------------------------------------------------------------------
// Kernel 3: histogram of obj
// ---------------------------------------------------------------------------
__global__ __launch_bounds__(256) void count_edges(const int* __restrict__ edges,
                                                   int* __restrict__ count) {
    const int e = blockIdx.x * 256 + threadIdx.x;
    if (e < N_EDGE) {
        const int obj = edges[(size_t)e * 7 + 6];
        atomicAdd(&count[obj], 1);
    }
}

// ---------------------------------------------------------------------------
// Kernel 4a/4b/4c: 3-phase parallel exclusive scan
// ---------------------------------------------------------------------------
__global__ __launch_bounds__(SCAN_BLK) void scan_partial(const int* __restrict__ count,
                                                         int* __restrict__ partial) {
    __shared__ int lds[SCAN_BLK];
    const int i = blockIdx.x * SCAN_BLK + threadIdx.x;
    lds[threadIdx.x] = (i < N_NODE) ? count[i] : 0;
    __syncthreads();
    for (int s = SCAN_BLK / 2; s > 0; s >>= 1) {
        if (threadIdx.x < s) lds[threadIdx.x] += lds[threadIdx.x + s];
        __syncthreads();
    }
    if (threadIdx.x == 0) partial[blockIdx.x] = lds[0];
}

__global__ __launch_bounds__(512) void scan_partials(const int* __restrict__ partial,
                                                     int* __restrict__ blk_off) {
    __shared__ int lds[512];
    const int t = threadIdx.x;
    lds[t] = (t < N_SCAN_BLKS) ? partial[t] : 0;
    __syncthreads();
    for (int d = 1; d < 512; d <<= 1) {
        int v = (t >= d) ? lds[t - d] : 0;
        __syncthreads();
        lds[t] += v;
        __syncthreads();
    }
    if (t < N_SCAN_BLKS) blk_off[t] = (t == 0) ? 0 : lds[t - 1];
}

__global__ __launch_bounds__(SCAN_BLK) void scan_apply(const int* __restrict__ count,
                                                       const int* __restrict__ blk_off,
                                                       int* __restrict__ off,
                                                       int* __restrict__ cursor) {
    __shared__ int lds[SCAN_BLK];
    const int t = threadIdx.x;
    const int i = blockIdx.x * SCAN_BLK + t;
    const int v = (i < N_NODE) ? count[i] : 0;
    lds[t] = v;
    __syncthreads();
    for (int d = 1; d < SCAN_BLK; d <<= 1) {
        int x = (t >= d) ? lds[t - d] : 0;
        __syncthreads();
        lds[t] += x;
        __syncthreads();
    }
    const int excl = blk_off[blockIdx.x] + lds[t] - v;
    if (i < N_NODE) { off[i] = excl; cursor[i] = excl; }
    if (i == N_NODE - 1) off[N_NODE] = excl + v;   // = N_EDGE
}

// ---------------------------------------------------------------------------
// Kernel 5: per-edge alpha + CSR fill. TWO edges per wave (half-wave each).
// Lane l (&31) handles attn dims 2l, 2l+1 via packed bf16 loads.
// ---------------------------------------------------------------------------
__global__ __launch_bounds__(256) void alpha_fill(const int* __restrict__ edges,
                                                  const int* __restrict__ q_tau_p,
                                                  const uint* __restrict__ A_node_bf,
                                                  const uint* __restrict__ rel_attn_bf,
                                                  const uint* __restrict__ qr_attn_bf,
                                                  const uint* __restrict__ tau_attn_bf,
                                                  const float* __restrict__ w_alpha_w,
                                                  const float* __restrict__ w_alpha_b,
                                                  int* __restrict__ cursor,
                                                  int4* __restrict__ recs) {
    const int half = threadIdx.x >> 5;          // 0..7 (edge within block)
    const int l    = threadIdx.x & 31;          // dims 2l, 2l+1
    const int e = blockIdx.x * 8 + half;
    const int* ed = edges + (size_t)e * 7;
    const int r_idx = ed[0];
    const int rel   = ed[2];
    const int tau   = ed[4];
    const int sub   = ed[5];
    const int obj   = ed[6];
    const int q_tau = *q_tau_p;
    const int tidx  = (tau >= 0) ? tau : q_tau;

    const uint ua = A_node_bf[(size_t)sub * 32 + l];
    const uint ur = rel_attn_bf[rel * 32 + l];
    const uint uq = qr_attn_bf[r_idx * 32 + l];
    const uint ut = tau_attn_bf[tidx * 32 + l];
    const float2 wa = ((const float2*)w_alpha_w)[l];

    const float x0 = bfl(ua) + bfl(ur) + bfl(uq) + bfl(ut);
    const float x1 = bfh(ua) + bfh(ur) + bfh(uq) + bfh(ut);
    float a = fmaxf(x0, 0.f) * wa.x + fmaxf(x1, 0.f) * wa.y;
    #pragma unroll
    for (int o = 16; o > 0; o >>= 1)
        a += __shfl_xor(a, o, 64);              // stays within the 32-lane half
    if (l == 0) {
        const float alpha = 1.f / (1.f + __expf(-(a + w_alpha_b[0])));
        const int pos = atomicAdd(&cursor[obj], 1);
        recs[pos] = make_int4(sub, rel, tidx, __float_as_int(alpha));
    }
}

// ---------------------------------------------------------------------------
// Kernel 6: per-node gather-aggregate (bf16 tables), unrolled by 2 edges.
// Writes bf16 agg rows: half0 = sum(alpha*m), half1 = sum((1-alpha)*m).
// ---------------------------------------------------------------------------
__global__ __launch_bounds__(256) void aggregate(const int* __restrict__ off,
                                                 const int4* __restrict__ recs,
                                                 const uint* __restrict__ hid_bf,
                                                 const uint* __restrict__ rel_msg_bf,
                                                 const uint* __restrict__ tau_msg_bf,
                                                 uint* __restrict__ agg_bf) {
    const int wave = threadIdx.x >> 6;
    const int lane = threadIdx.x & 63;          // dims 2*lane, 2*lane+1
    const int n = blockIdx.x * 4 + wave;
    const int j0 = off[n];
    const int j1 = off[n + 1];

    float t0 = 0.f, t1 = 0.f;   // sum m
    float a0 = 0.f, a1 = 0.f;   // sum alpha*m
    int j = j0;
    for (; j + 1 < j1; j += 2) {
        const int4 rA = recs[j];
        const int4 rB = recs[j + 1];
        const uint hA = hid_bf[(size_t)rA.x * 64 + lane];
        const uint hB = hid_bf[(size_t)rB.x * 64 + lane];
        const uint eA = rel_msg_bf[rA.y * 64 + lane];
        const uint eB = rel_msg_bf[rB.y * 64 + lane];
        const uint uA = tau_msg_bf[rA.z * 64 + lane];
        const uint uB = tau_msg_bf[rB.z * 64 + lane];
        const float alA = __int_as_float(rA.w);
        const float alB = __int_as_float(rB.w);
        const float m0A = bfl(hA) + bfl(eA) + bfl(uA);
        const float m1A = bfh(hA) + bfh(eA) + bfh(uA);
        const float m0B = bfl(hB) + bfl(eB) + bfl(uB);
        const float m1B = bfh(hB) + bfh(eB) + bfh(uB);
        t0 += m0A + m0B;  t1 += m1A + m1B;
        a0 = fmaf(alA, m0A, fmaf(alB, m0B, a0));
        a1 = fmaf(alA, m1A, fmaf(alB, m1B, a1));
    }
    if (j < j1) {
        const int4 rA = recs[j];
        const uint hA = hid_bf[(size_t)rA.x * 64 + lane];
        const uint eA = rel_msg_bf[rA.y * 64 + lane];
        const uint uA = tau_msg_bf[rA.z * 64 + lane];
        const float alA = __int_as_float(rA.w);
        const float m0A = bfl(hA) + bfl(eA) + bfl(uA);
        const float m1A = bfh(hA) + bfh(eA) + bfh(uA);
        t0 += m0A;  t1 += m1A;
        a0 = fmaf(alA, m0A, a0);
        a1 = fmaf(alA, m1A, a1);
    }
    agg_bf[(size_t)n * 64 + lane] = pack2(a0, a1);
    agg_bf[(size_t)(N_NODE + n) * 64 + lane] = pack2(t0 - a0, t1 - a1);
}

// ---------------------------------------------------------------------------
// Kernel 7: MFMA GEMM  out[half] = agg_bf[half] @ W[half]  (fp32 out).
// mfma_f32_16x16x32_bf16; wave = 16 rows x 128 cols; block = 64 rows.
// A frag: lane(m=lane&15) reads 8 contiguous k. B frag from W^T (k-contig).
// D: col = lane&15, row = (lane>>4)*4 + reg  (m89-verified).
// ---------------------------------------------------------------------------
__global__ __launch_bounds__(256) void final_gemm_mfma(const uint* __restrict__ agg_bf,
                                                       const ushort* __restrict__ wT_bf,
                                                       float* __restrict__ out) {
    const int halfsel = blockIdx.y;
    const ushort* W = wT_bf + (size_t)halfsel * 128 * 128;
    const ushort* A = (const ushort*)(agg_bf + (size_t)halfsel * N_NODE * 64);
    float* O = out + (size_t)halfsel * N_NODE * 128;

    const int wave = threadIdx.x >> 6;
    const int lane = threadIdx.x & 63;
    const int m    = lane & 15;
    const int quad = lane >> 4;
    const int row0 = blockIdx.x * 64 + wave * 16;

    const int rowA = min(row0 + m, N_NODE - 1);
    const ushort* arow = A + (size_t)rowA * 128;

    f32x4 acc[8] = {};
    #pragma unroll
    for (int ks = 0; ks < 4; ++ks) {
        const bf16x8 a = *(const bf16x8*)(arow + ks * 32 + quad * 8);
        #pragma unroll
        for (int ct = 0; ct < 8; ++ct) {
            const bf16x8 bfr = *(const bf16x8*)(W + (ct * 16 + m) * 128 + ks * 32 + quad * 8);
            acc[ct] = __builtin_amdgcn_mfma_f32_16x16x32_bf16(a, bfr, acc[ct], 0, 0, 0);
        }
    }

    const int orow0 = row0 + quad * 4;
    #pragma unroll
    for (int ct = 0; ct < 8; ++ct) {
        #pragma unroll
        for (int r = 0; r < 4; ++r) {
            const int row = orow0 + r;
            if (row < N_NODE)
                O[(size_t)row * 128 + ct * 16 + m] = acc[ct][r];
        }
    }
}

// ---------------------------------------------------------------------------
extern "C" void kernel_launch(void* const* d_in, const int* in_sizes, int n_in,
                              void* d_out, int out_size, void* d_ws, size_t ws_size,
                              hipStream_t stream) {
    const int*   q_rel      = (const int*)d_in[1];
    const int*   q_tau_p    = (const int*)d_in[2];
    const float* hidden     = (const float*)d_in[3];
    const int*   edges      = (const int*)d_in[4];
    const float* rela_embed = (const float*)d_in[7];
    const float* Ws_w       = (const float*)d_in[8];
    const float* Wr_w       = (const float*)d_in[9];
    const float* Wqr_w      = (const float*)d_in[10];
    const float* Wqr_b      = (const float*)d_in[11];
    const float* Wtau_w     = (const float*)d_in[12];
    const float* w_alpha_w  = (const float*)d_in[13];
    const float* w_alpha_b  = (const float*)d_in[14];
    const float* W_h_w      = (const float*)d_in[15];
    const float* W_h_s_w    = (const float*)d_in[16];
    const float* w_t1       = (const float*)d_in[17];
    const float* b_t1       = (const float*)d_in[18];
    const float* w_t2       = (const float*)d_in[19];
    const float* b_t2       = (const float*)d_in[20];

    // ---- workspace layout (16B-aligned chunks) ----
    char* p = (char*)d_ws;
    uint* hid_bf      = (uint*)p;                 p += (size_t)N_NODE * 64 * 4;        // 25.6 MB
    uint* agg_bf      = (uint*)p;                 p += (size_t)2 * N_NODE * 64 * 4;    // 51.2 MB
    uint* A_node_bf   = (uint*)p;                 p += (size_t)N_NODE * 32 * 4;        // 12.8 MB
    int4* recs        = (int4*)p;                 p += (size_t)N_EDGE * 16;            // 8 MB
    uint* rel_attn_bf = (uint*)p;                 p += N_RELTAB * 32 * 4;
    uint* qr_attn_bf  = (uint*)p;                 p += N_QRY * 32 * 4;
    uint* tau_attn_bf = (uint*)p;                 p += N_TAU * 32 * 4;
    uint* rel_msg_bf  = (uint*)p;                 p += N_RELTAB * 64 * 4;
    uint* tau_msg_bf  = (uint*)p;                 p += N_TAU * 64 * 4;
    ushort* wT_bf     = (ushort*)p;               p += (size_t)2 * 128 * 128 * 2;      // 64 KB
    int*  count       = (int*)p;                  p += N_NODE * 4;
    int*  off         = (int*)p;                  p += (N_NODE + 1) * 4;
    int*  cursor      = (int*)p;                  p += N_NODE * 4;
    int*  partial     = (int*)p;                  p += N_SCAN_BLKS * 4;
    int*  blk_off     = (int*)p;                  p += N_SCAN_BLKS * 4;

    hipMemsetAsync(count, 0, (size_t)N_NODE * sizeof(int), stream);

    build_tables<<<dim3(N_TAU + N_RELTAB + N_QRY + 2), dim3(128), 0, stream>>>(
        q_rel, q_tau_p, rela_embed, Wr_w, Wqr_w, Wqr_b, Wtau_w,
        w_t1, b_t1, w_t2, b_t2, W_h_w, W_h_s_w,
        rel_attn_bf, qr_attn_bf, tau_attn_bf, rel_msg_bf, tau_msg_bf, wT_bf);

    node_attn<<<dim3(N_NODE / 4), dim3(256), 0, stream>>>(hidden, Ws_w, hid_bf, A_node_bf);

    count_edges<<<dim3((N_EDGE + 255) / 256), dim3(256), 0, stream>>>(edges, count);

    scan_partial<<<dim3(N_SCAN_BLKS), dim3(SCAN_BLK), 0, stream>>>(count, partial);
    scan_partials<<<dim3(1), dim3(512), 0, stream>>>(partial, blk_off);
    scan_apply<<<dim3(N_SCAN_BLKS), dim3(SCAN_BLK), 0, stream>>>(count, blk_off, off, cursor);

    alpha_fill<<<dim3(N_EDGE / 8), dim3(256), 0, stream>>>(
        edges, q_tau_p, A_node_bf, rel_attn_bf, qr_attn_bf, tau_attn_bf,
        w_alpha_w, w_alpha_b, cursor, recs);

    aggregate<<<dim3(N_NODE / 4), dim3(256), 0, stream>>>(
        off, recs, hid_bf, rel_msg_bf, tau_msg_bf, agg_bf);

    final_gemm_mfma<<<dim3((N_NODE + 63) / 64, 2), dim3(256), 0, stream>>>(
        agg_bf, wT_bf, (float*)d_out);
}

// Round 5
// 412.532 us; speedup vs baseline: 2.1861x; 1.2310x over previous
//
#include <hip/hip_runtime.h>
#include <math.h>

#define N_NODE   100000
#define N_EDGE   500000
#define IN_DIM   128
#define OUT_DIM  128
#define ATTN_DIM 64
#define N_RELTAB 401   // 2*N_REL+1
#define N_QRY    64
#define N_TAU    366

#define SCAN_BLK     256
#define N_SCAN_BLKS  ((N_NODE + SCAN_BLK - 1) / SCAN_BLK)   // 391

typedef unsigned int  uint;
typedef unsigned short ushort;
typedef __attribute__((ext_vector_type(8))) short bf16x8;
typedef __attribute__((ext_vector_type(4))) float f32x4;

// ---- bf16 helpers (RNE) ----------------------------------------------------
__device__ __forceinline__ float bfl(uint u)  { return __uint_as_float(u << 16); }
__device__ __forceinline__ float bfh(uint u)  { return __uint_as_float(u & 0xFFFF0000u); }
__device__ __forceinline__ uint  f2bfbits(float f) {
    uint u = __float_as_uint(f);
    return (u + 0x7FFFu + ((u >> 16) & 1u)) >> 16;
}
__device__ __forceinline__ uint  pack2(float lo, float hi) {
    return f2bfbits(lo) | (f2bfbits(hi) << 16);
}

// ---------------------------------------------------------------------------
// Kernel 1: build small lookup tables (all bf16):
//   tau blocks:  tau_msg_bf row (128 dims) + tau_attn_bf row (64 dims)
//   rel blocks:  rel_msg_bf row + rel_attn_bf row
//   qr  blocks:  qr_attn_bf row
//   3 W blocks:  wT_bf = {W_h, W_h_s}^T and wsT_bf = Ws^T (n-major, k-contig)
// ---------------------------------------------------------------------------
__global__ void build_tables(const int* __restrict__ q_rel,
                             const int* __restrict__ q_tau_p,
                             const float* __restrict__ rela_embed,
                             const float* __restrict__ Wr_w,
                             const float* __restrict__ Wqr_w,
                             const float* __restrict__ Wqr_b,
                             const float* __restrict__ Wtau_w,
                             const float* __restrict__ w_t1,
                             const float* __restrict__ b_t1,
                             const float* __restrict__ w_t2,
                             const float* __restrict__ b_t2,
                             const float* __restrict__ W_h_w,
                             const float* __restrict__ W_h_s_w,
                             const float* __restrict__ Ws_w,
                             uint* __restrict__ rel_attn_bf,   // [401][32]
                             uint* __restrict__ qr_attn_bf,    // [64][32]
                             uint* __restrict__ tau_attn_bf,   // [366][32]
                             uint* __restrict__ rel_msg_bf,    // [401][64]
                             uint* __restrict__ tau_msg_bf,    // [366][64]
                             ushort* __restrict__ wT_bf,       // [2][128][128]
                             ushort* __restrict__ wsT_bf) {    // [64][128]
    __shared__ float srow[IN_DIM];
    __shared__ float sattn[ATTN_DIM];
    const int b = blockIdx.x;
    const int t = threadIdx.x;   // 0..127

    if (b < N_TAU) {
        const int q_tau = *q_tau_p;
        const float delta = (float)(b - q_tau);
        float v = w_t1[t] * delta + b_t1[t] + sinf(w_t2[t] * delta + b_t2[t]);
        srow[t] = v;
        __syncthreads();
        if (t < 64) tau_msg_bf[b * 64 + t] = pack2(srow[2 * t], srow[2 * t + 1]);
        if (t < ATTN_DIM) {
            float acc = 0.f;
            #pragma unroll 8
            for (int d = 0; d < IN_DIM; ++d)
                acc += srow[d] * Wtau_w[d * ATTN_DIM + t];
            sattn[t] = acc;
        }
        __syncthreads();
        if (t < 32) tau_attn_bf[b * 32 + t] = pack2(sattn[2 * t], sattn[2 * t + 1]);
    } else if (b < N_TAU + N_RELTAB) {
        const int r = b - N_TAU;
        srow[t] = rela_embed[r * IN_DIM + t];
        __syncthreads();
        if (t < 64) rel_msg_bf[r * 64 + t] = pack2(srow[2 * t], srow[2 * t + 1]);
        if (t < ATTN_DIM) {
            float acc = 0.f;
            #pragma unroll 8
            for (int d = 0; d < IN_DIM; ++d)
                acc += srow[d] * Wr_w[d * ATTN_DIM + t];
            sattn[t] = acc;
        }
        __syncthreads();
        if (t < 32) rel_attn_bf[r * 32 + t] = pack2(sattn[2 * t], sattn[2 * t + 1]);
    } else if (b < N_TAU + N_RELTAB + N_QRY) {
        const int i = b - N_TAU - N_RELTAB;   // 0..63
        const int r = q_rel[i];
        srow[t] = rela_embed[r * IN_DIM + t];
        __syncthreads();
        if (t < ATTN_DIM) {
            float acc = Wqr_b[t];
            #pragma unroll 8
            for (int d = 0; d < IN_DIM; ++d)
                acc += srow[d] * Wqr_w[d * ATTN_DIM + t];
            sattn[t] = acc;
        }
        __syncthreads();
        if (t < 32) qr_attn_bf[i * 32 + t] = pack2(sattn[2 * t], sattn[2 * t + 1]);
    } else {
        const int w = b - (N_TAU + N_RELTAB + N_QRY);   // 0,1,2
        if (w < 2) {
            const float* Wsrc = w ? W_h_s_w : W_h_w;
            ushort* dst = wT_bf + (size_t)w * 128 * 128;
            for (int k = 0; k < 128; ++k)
                dst[t * 128 + k] = (ushort)f2bfbits(Wsrc[k * 128 + t]);
        } else {
            // Ws^T: [n=0..63][k=0..127], thread t = k index
            for (int n = 0; n < 64; ++n)
                wsT_bf[n * 128 + t] = (ushort)f2bfbits(Ws_w[t * ATTN_DIM + n]);
        }
    }
}

// ---------------------------------------------------------------------------
// Kernel 2: fused cast + MFMA  A_node = bf16(hidden) @ Ws  (100k x 128 @ 128 x 64)
// Wave = 16 rows. Loads fp32 hidden, converts in-register, writes hid_bf row,
// feeds the same regs to mfma_f32_16x16x32_bf16. No shuffles, no LDS.
// ---------------------------------------------------------------------------
__global__ __launch_bounds__(256) void node_attn_mfma(const float* __restrict__ hidden,
                                                      const ushort* __restrict__ wsT_bf,
                                                      uint* __restrict__ hid_bf_u,    // [N][64] uints
                                                      ushort* __restrict__ A_node) {  // [N][64] ushorts
    const int wave = threadIdx.x >> 6;
    const int lane = threadIdx.x & 63;
    const int m    = lane & 15;
    const int quad = lane >> 4;
    const int row0 = blockIdx.x * 64 + wave * 16;
    const int row  = row0 + m;
    const int rowc = min(row, N_NODE - 1);

    const float* hsrc = hidden + (size_t)rowc * IN_DIM;
    ushort* hdst = (ushort*)hid_bf_u + (size_t)rowc * 128;

    bf16x8 afr[4];
    #pragma unroll
    for (int ks = 0; ks < 4; ++ks) {
        const int k0 = ks * 32 + quad * 8;
        const float4 v0 = *(const float4*)(hsrc + k0);
        const float4 v1 = *(const float4*)(hsrc + k0 + 4);
        union { uint u[4]; bf16x8 v; } cvt;
        cvt.u[0] = pack2(v0.x, v0.y);
        cvt.u[1] = pack2(v0.z, v0.w);
        cvt.u[2] = pack2(v1.x, v1.y);
        cvt.u[3] = pack2(v1.z, v1.w);
        afr[ks] = cvt.v;
        if (row < N_NODE) *(bf16x8*)(hdst + k0) = cvt.v;   // 16B store
    }

    f32x4 acc[4] = {};
    #pragma unroll
    for (int ks = 0; ks < 4; ++ks) {
        #pragma unroll
        for (int ct = 0; ct < 4; ++ct) {
            const bf16x8 bfr = *(const bf16x8*)(wsT_bf + (ct * 16 + m) * 128 + ks * 32 + quad * 8);
            acc[ct] = __builtin_amdgcn_mfma_f32_16x16x32_bf16(afr[ks], bfr, acc[ct], 0, 0, 0);
        }
    }

    // D: col = lane&15, row = quad*4 + reg
    #pragma unroll
    for (int ct = 0; ct < 4; ++ct) {
        #pragma unroll
        for (int r = 0; r < 4; ++r) {
            const int orow = row0 + quad * 4 + r;
            if (orow < N_NODE)
                A_node[(size_t)orow * 64 + ct * 16 + m] = (ushort)f2bfbits(acc[ct][r]);
        }
    }
}

// ---------------------------------------------------------------------------
// Kernel 3: histogram of obj
// ---------------------------------------------------------------------------
__global__ __launch_bounds__(256) void count_edges(const int* __restrict__ edges,
                                                   int* __restrict__ count) {
    const int e = blockIdx.x * 256 + threadIdx.x;
    if (e < N_EDGE) {
        const int obj = edges[(size_t)e * 7 + 6];
        atomicAdd(&count[obj], 1);
    }
}

// ---------------------------------------------------------------------------
// Kernel 4a/4b/4c: 3-phase parallel exclusive scan
// ---------------------------------------------------------------------------
__global__ __launch_bounds__(SCAN_BLK) void scan_partial(const int* __restrict__ count,
                                                         int* __restrict__ partial) {
    __shared__ int lds[SCAN_BLK];
    const int i = blockIdx.x * SCAN_BLK + threadIdx.x;
    lds[threadIdx.x] = (i < N_NODE) ? count[i] : 0;
    __syncthreads();
    for (int s = SCAN_BLK / 2; s > 0; s >>= 1) {
        if (threadIdx.x < s) lds[threadIdx.x] += lds[threadIdx.x + s];
        __syncthreads();
    }
    if (threadIdx.x == 0) partial[blockIdx.x] = lds[0];
}

__global__ __launch_bounds__(512) void scan_partials(const int* __restrict__ partial,
                                                     int* __restrict__ blk_off) {
    __shared__ int lds[512];
    const int t = threadIdx.x;
    lds[t] = (t < N_SCAN_BLKS) ? partial[t] : 0;
    __syncthreads();
    for (int d = 1; d < 512; d <<= 1) {
        int v = (t >= d) ? lds[t - d] : 0;
        __syncthreads();
        lds[t] += v;
        __syncthreads();
    }
    if (t < N_SCAN_BLKS) blk_off[t] = (t == 0) ? 0 : lds[t - 1];
}

__global__ __launch_bounds__(SCAN_BLK) void scan_apply(const int* __restrict__ count,
                                                       const int* __restrict__ blk_off,
                                                       int* __restrict__ off,
                                                       int* __restrict__ cursor) {
    __shared__ int lds[SCAN_BLK];
    const int t = threadIdx.x;
    const int i = blockIdx.x * SCAN_BLK + t;
    const int v = (i < N_NODE) ? count[i] : 0;
    lds[t] = v;
    __syncthreads();
    for (int d = 1; d < SCAN_BLK; d <<= 1) {
        int x = (t >= d) ? lds[t - d] : 0;
        __syncthreads();
        lds[t] += x;
        __syncthreads();
    }
    const int excl = blk_off[blockIdx.x] + lds[t] - v;
    if (i < N_NODE) { off[i] = excl; cursor[i] = excl; }
    if (i == N_NODE - 1) off[N_NODE] = excl + v;   // = N_EDGE
}

// ---------------------------------------------------------------------------
// Kernel 5: per-edge alpha + CSR fill. TWO edges per wave (half-wave each).
// ---------------------------------------------------------------------------
__global__ __launch_bounds__(256) void alpha_fill(const int* __restrict__ edges,
                                                  const int* __restrict__ q_tau_p,
                                                  const uint* __restrict__ A_node_bf,
                                                  const uint* __restrict__ rel_attn_bf,
                                                  const uint* __restrict__ qr_attn_bf,
                                                  const uint* __restrict__ tau_attn_bf,
                                                  const float* __restrict__ w_alpha_w,
                                                  const float* __restrict__ w_alpha_b,
                                                  int* __restrict__ cursor,
                                                  int4* __restrict__ recs) {
    const int half = threadIdx.x >> 5;          // 0..7 (edge within block)
    const int l    = threadIdx.x & 31;          // dims 2l, 2l+1
    const int e = blockIdx.x * 8 + half;
    const int* ed = edges + (size_t)e * 7;
    const int r_idx = ed[0];
    const int rel   = ed[2];
    const int tau   = ed[4];
    const int sub   = ed[5];
    const int obj   = ed[6];
    const int q_tau = *q_tau_p;
    const int tidx  = (tau >= 0) ? tau : q_tau;

    const uint ua = A_node_bf[(size_t)sub * 32 + l];
    const uint ur = rel_attn_bf[rel * 32 + l];
    const uint uq = qr_attn_bf[r_idx * 32 + l];
    const uint ut = tau_attn_bf[tidx * 32 + l];
    const float2 wa = ((const float2*)w_alpha_w)[l];

    const float x0 = bfl(ua) + bfl(ur) + bfl(uq) + bfl(ut);
    const float x1 = bfh(ua) + bfh(ur) + bfh(uq) + bfh(ut);
    float a = fmaxf(x0, 0.f) * wa.x + fmaxf(x1, 0.f) * wa.y;
    #pragma unroll
    for (int o = 16; o > 0; o >>= 1)
        a += __shfl_xor(a, o, 64);              // stays within the 32-lane half
    if (l == 0) {
        const float alpha = 1.f / (1.f + __expf(-(a + w_alpha_b[0])));
        const int pos = atomicAdd(&cursor[obj], 1);
        recs[pos] = make_int4(sub, rel, tidx, __float_as_int(alpha));
    }
}

// ---------------------------------------------------------------------------
// Kernel 6: per-node gather-aggregate (bf16 tables), unrolled by 2 edges.
// ---------------------------------------------------------------------------
__global__ __launch_bounds__(256) void aggregate(const int* __restrict__ off,
                                                 const int4* __restrict__ recs,
                                                 const uint* __restrict__ hid_bf,
                                                 const uint* __restrict__ rel_msg_bf,
                                                 const uint* __restrict__ tau_msg_bf,
                                                 uint* __restrict__ agg_bf) {
    const int wave = threadIdx.x >> 6;
    const int lane = threadIdx.x & 63;          // dims 2*lane, 2*lane+1
    const int n = blockIdx.x * 4 + wave;
    const int j0 = off[n];
    const int j1 = off[n + 1];

    float t0 = 0.f, t1 = 0.f;   // sum m
    float a0 = 0.f, a1 = 0.f;   // sum alpha*m
    int j = j0;
    for (; j + 1 < j1; j += 2) {
        const int4 rA = recs[j];
        const int4 rB = recs[j + 1];
        const uint hA = hid_bf[(size_t)rA.x * 64 + lane];
        const uint hB = hid_bf[(size_t)rB.x * 64 + lane];
        const uint eA = rel_msg_bf[rA.y * 64 + lane];
        const uint eB = rel_msg_bf[rB.y * 64 + lane];
        const uint uA = tau_msg_bf[rA.z * 64 + lane];
        const uint uB = tau_msg_bf[rB.z * 64 + lane];
        const float alA = __int_as_float(rA.w);
        const float alB = __int_as_float(rB.w);
        const float m0A = bfl(hA) + bfl(eA) + bfl(uA);
        const float m1A = bfh(hA) + bfh(eA) + bfh(uA);
        const float m0B = bfl(hB) + bfl(eB) + bfl(uB);
        const float m1B = bfh(hB) + bfh(eB) + bfh(uB);
        t0 += m0A + m0B;  t1 += m1A + m1B;
        a0 = fmaf(alA, m0A, fmaf(alB, m0B, a0));
        a1 = fmaf(alA, m1A, fmaf(alB, m1B, a1));
    }
    if (j < j1) {
        const int4 rA = recs[j];
        const uint hA = hid_bf[(size_t)rA.x * 64 + lane];
        const uint eA = rel_msg_bf[rA.y * 64 + lane];
        const uint uA = tau_msg_bf[rA.z * 64 + lane];
        const float alA = __int_as_float(rA.w);
        const float m0A = bfl(hA) + bfl(eA) + bfl(uA);
        const float m1A = bfh(hA) + bfh(eA) + bfh(uA);
        t0 += m0A;  t1 += m1A;
        a0 = fmaf(alA, m0A, a0);
        a1 = fmaf(alA, m1A, a1);
    }
    agg_bf[(size_t)n * 64 + lane] = pack2(a0, a1);
    agg_bf[(size_t)(N_NODE + n) * 64 + lane] = pack2(t0 - a0, t1 - a1);
}

// ---------------------------------------------------------------------------
// Kernel 7: MFMA GEMM  out[half] = agg_bf[half] @ W[half]  (fp32 out).
// ---------------------------------------------------------------------------
__global__ __launch_bounds__(256) void final_gemm_mfma(const uint* __restrict__ agg_bf,
                                                       const ushort* __restrict__ wT_bf,
                                                       float* __restrict__ out) {
    const int halfsel = blockIdx.y;
    const ushort* W = wT_bf + (size_t)halfsel * 128 * 128;
    const ushort* A = (const ushort*)(agg_bf + (size_t)halfsel * N_NODE * 64);
    float* O = out + (size_t)halfsel * N_NODE * 128;

    const int wave = threadIdx.x >> 6;
    const int lane = threadIdx.x & 63;
    const int m    = lane & 15;
    const int quad = lane >> 4;
    const int row0 = blockIdx.x * 64 + wave * 16;

    const int rowA = min(row0 + m, N_NODE - 1);
    const ushort* arow = A + (size_t)rowA * 128;

    f32x4 acc[8] = {};
    #pragma unroll
    for (int ks = 0; ks < 4; ++ks) {
        const bf16x8 a = *(const bf16x8*)(arow + ks * 32 + quad * 8);
        #pragma unroll
        for (int ct = 0; ct < 8; ++ct) {
            const bf16x8 bfr = *(const bf16x8*)(W + (ct * 16 + m) * 128 + ks * 32 + quad * 8);
            acc[ct] = __builtin_amdgcn_mfma_f32_16x16x32_bf16(a, bfr, acc[ct], 0, 0, 0);
        }
    }

    const int orow0 = row0 + quad * 4;
    #pragma unroll
    for (int ct = 0; ct < 8; ++ct) {
        #pragma unroll
        for (int r = 0; r < 4; ++r) {
            const int row = orow0 + r;
            if (row < N_NODE)
                O[(size_t)row * 128 + ct * 16 + m] = acc[ct][r];
        }
    }
}

// ---------------------------------------------------------------------------
extern "C" void kernel_launch(void* const* d_in, const int* in_sizes, int n_in,
                              void* d_out, int out_size, void* d_ws, size_t ws_size,
                              hipStream_t stream) {
    const int*   q_rel      = (const int*)d_in[1];
    const int*   q_tau_p    = (const int*)d_in[2];
    const float* hidden     = (const float*)d_in[3];
    const int*   edges      = (const int*)d_in[4];
    const float* rela_embed = (const float*)d_in[7];
    const float* Ws_w       = (const float*)d_in[8];
    const float* Wr_w       = (const float*)d_in[9];
    const float* Wqr_w      = (const float*)d_in[10];
    const float* Wqr_b      = (const float*)d_in[11];
    const float* Wtau_w     = (const float*)d_in[12];
    const float* w_alpha_w  = (const float*)d_in[13];
    const float* w_alpha_b  = (const float*)d_in[14];
    const float* W_h_w      = (const float*)d_in[15];
    const float* W_h_s_w    = (const float*)d_in[16];
    const float* w_t1       = (const float*)d_in[17];
    const float* b_t1       = (const float*)d_in[18];
    const float* w_t2       = (const float*)d_in[19];
    const float* b_t2       = (const float*)d_in[20];

    // ---- workspace layout (16B-aligned chunks) ----
    char* p = (char*)d_ws;
    uint* hid_bf      = (uint*)p;                 p += (size_t)N_NODE * 64 * 4;        // 25.6 MB
    uint* agg_bf      = (uint*)p;                 p += (size_t)2 * N_NODE * 64 * 4;    // 51.2 MB
    uint* A_node_bf   = (uint*)p;                 p += (size_t)N_NODE * 32 * 4;        // 12.8 MB
    int4* recs        = (int4*)p;                 p += (size_t)N_EDGE * 16;            // 8 MB
    uint* rel_attn_bf = (uint*)p;                 p += N_RELTAB * 32 * 4;
    uint* qr_attn_bf  = (uint*)p;                 p += N_QRY * 32 * 4;
    uint* tau_attn_bf = (uint*)p;                 p += N_TAU * 32 * 4;
    uint* rel_msg_bf  = (uint*)p;                 p += N_RELTAB * 64 * 4;
    uint* tau_msg_bf  = (uint*)p;                 p += N_TAU * 64 * 4;
    ushort* wT_bf     = (ushort*)p;               p += (size_t)2 * 128 * 128 * 2;      // 64 KB
    ushort* wsT_bf    = (ushort*)p;               p += (size_t)64 * 128 * 2;           // 16 KB
    int*  count       = (int*)p;                  p += N_NODE * 4;
    int*  off         = (int*)p;                  p += (N_NODE + 1) * 4;
    int*  cursor      = (int*)p;                  p += N_NODE * 4;
    int*  partial     = (int*)p;                  p += N_SCAN_BLKS * 4;
    int*  blk_off     = (int*)p;                  p += N_SCAN_BLKS * 4;

    hipMemsetAsync(count, 0, (size_t)N_NODE * sizeof(int), stream);

    build_tables<<<dim3(N_TAU + N_RELTAB + N_QRY + 3), dim3(128), 0, stream>>>(
        q_rel, q_tau_p, rela_embed, Wr_w, Wqr_w, Wqr_b, Wtau_w,
        w_t1, b_t1, w_t2, b_t2, W_h_w, W_h_s_w, Ws_w,
        rel_attn_bf, qr_attn_bf, tau_attn_bf, rel_msg_bf, tau_msg_bf, wT_bf, wsT_bf);

    node_attn_mfma<<<dim3((N_NODE + 63) / 64), dim3(256), 0, stream>>>(
        hidden, wsT_bf, hid_bf, (ushort*)A_node_bf);

    count_edges<<<dim3((N_EDGE + 255) / 256), dim3(256), 0, stream>>>(edges, count);

    scan_partial<<<dim3(N_SCAN_BLKS), dim3(SCAN_BLK), 0, stream>>>(count, partial);
    scan_partials<<<dim3(1), dim3(512), 0, stream>>>(partial, blk_off);
    scan_apply<<<dim3(N_SCAN_BLKS), dim3(SCAN_BLK), 0, stream>>>(count, blk_off, off, cursor);

    alpha_fill<<<dim3(N_EDGE / 8), dim3(256), 0, stream>>>(
        edges, q_tau_p, A_node_bf, rel_attn_bf, qr_attn_bf, tau_attn_bf,
        w_alpha_w, w_alpha_b, cursor, recs);

    aggregate<<<dim3(N_NODE / 4), dim3(256), 0, stream>>>(
        off, recs, hid_bf, rel_msg_bf, tau_msg_bf, agg_bf);

    final_gemm_mfma<<<dim3((N_NODE + 63) / 64, 2), dim3(256), 0, stream>>>(
        agg_bf, wT_bf, (float*)d_out);
}